// Round 8
// baseline (3101.659 us; speedup 1.0000x reference)
//
#include <hip/hip_runtime.h>
#include <stdint.h>

#define TT 512
#define BB 256
#define HH 512
#define NOUTC 64
// 16 groups x 16 blocks; each block: 16 batch x 128 gate rows.

typedef _Float16 f16;
typedef f16 f16x8 __attribute__((ext_vector_type(8)));
typedef float f32x4 __attribute__((ext_vector_type(4)));
typedef unsigned long long ull;

__device__ __forceinline__ float sigmoidf_(float x) {
  x = fminf(fmaxf(x, -30.f), 30.f);
  return 1.f / (1.f + __expf(-x));
}
__device__ __forceinline__ float tanhf_(float x) {
  x = fminf(fmaxf(x, -15.f), 15.f);
  float e = __expf(2.f * x);
  return (e - 1.f) / (e + 1.f);
}

// Zero the ws region (flag array + h double-buffer).
__global__ void zero_ws(uint32_t* __restrict__ ws, int nws) {
  int idx = blockIdx.x * blockDim.x + threadIdx.x;
  int stride = gridDim.x * blockDim.x;
  for (int i = idx; i < nws; i += stride) ws[i] = 0u;
}

// R7 change: h staging was 2048x 8B agent-atomic MALL transactions per block
// per step (~524K/step device-wide — the dominant serial cost). Now: relaxed
// flag spin -> ONE agent acquire fence (buffer_inv; drops stale L1/L2 copies
// of the prior same-parity buffer) -> plain cached uint4 loads (64B line
// fills, 8x fewer transactions). Publish stays 8B agent write-through atomic
// (128/block/step) so correctness never depends on XCD placement.
__global__ __launch_bounds__(256, 1) void lstm_kernel(
    const float* __restrict__ input, const float* __restrict__ dtp,
    const float* __restrict__ W_ih, const float* __restrict__ W_hh,
    const float* __restrict__ b_ih, const float* __restrict__ b_hh,
    const float* __restrict__ W_cls, const float* __restrict__ b_cls,
    float* __restrict__ out, uint32_t* __restrict__ flg,
    f16* __restrict__ h_buf) {
  __shared__ __align__(16) f16 xh[16][648];         // [n][k: 128 x | 512 h]
  __shared__ __align__(16) float gates_s[128][17];  // [q*32 + hl][n]
  __shared__ __align__(16) f16 h_tile[16][40];      // [n][hl], padded
  __shared__ __align__(16) float red[4][16][17];    // classifier wave partials
  __shared__ float bias_s[128];

  const int tid = threadIdx.x;
  const int g = blockIdx.x & 15;   // group: batch slice [g*16, g*16+16)
  const int s = blockIdx.x >> 4;   // sub: hidden slice [s*32, s*32+32)
  const int b0 = g * 16;
  const int w = tid >> 6;          // wave id 0..3 == gate q (i,f,g,o)
  const int lane = tid & 63;
  const int l = lane & 15;
  const int quad = lane >> 4;

  // classifier role (blocks s<4): out-rows [s*16, s*16+16), K=512 over waves.
  const int mt_o = s & 3;
  const bool cls_block = (s < 4);

  // ---- A-fragments: wave w owns gate w, hidden-local [0,32) = 2 m-tiles.
  f16x8 afrag[2][20];
#pragma unroll
  for (int mp = 0; mp < 2; ++mp) {
    const int grow = w * HH + s * 32 + mp * 16 + l;  // gate row in [0,2048)
#pragma unroll
    for (int it = 0; it < 20; ++it) {
      const int kb = it * 32 + quad * 8;
      const float* src = (kb < 128) ? (W_ih + (size_t)grow * 128 + kb)
                                    : (W_hh + (size_t)grow * HH + (kb - 128));
      float4 p0 = *(const float4*)(src);
      float4 p1 = *(const float4*)(src + 4);
      f16x8 a;
      a[0] = (f16)p0.x; a[1] = (f16)p0.y; a[2] = (f16)p0.z; a[3] = (f16)p0.w;
      a[4] = (f16)p1.x; a[5] = (f16)p1.y; a[6] = (f16)p1.z; a[7] = (f16)p1.w;
      afrag[mp][it] = a;
    }
  }
  // ---- W_cls fragments: wave w owns K-chunk [w*128, (w+1)*128) (s<4 only)
  f16x8 wfrag[4];
  if (cls_block) {
#pragma unroll
    for (int it = 0; it < 4; ++it) {
      const int kb = w * 128 + it * 32 + quad * 8;
      const float* src = W_cls + (size_t)(mt_o * 16 + l) * HH + kb;
      float4 p0 = *(const float4*)(src);
      float4 p1 = *(const float4*)(src + 4);
      f16x8 a;
      a[0] = (f16)p0.x; a[1] = (f16)p0.y; a[2] = (f16)p0.z; a[3] = (f16)p0.w;
      a[4] = (f16)p1.x; a[5] = (f16)p1.y; a[6] = (f16)p1.z; a[7] = (f16)p1.w;
      wfrag[it] = a;
    }
  }
  float bcls4[4] = {0.f, 0.f, 0.f, 0.f};
  if (cls_block && tid < 64) {
    const int m4 = (tid & 3) * 4;
#pragma unroll
    for (int r = 0; r < 4; ++r) bcls4[r] = b_cls[mt_o * 16 + m4 + r];
  }

  if (tid < 128) {  // bias row = q*32 + hl
    const int grow = (tid >> 5) * HH + s * 32 + (tid & 31);
    bias_s[tid] = b_ih[grow] + b_hh[grow];
  }

  // cell state: thread (hl = tid>>4, n = tid&15) and (hl+16, n)
  float c0 = 0.f, c1 = 0.f;

  for (int t = 0; t <= TT; ++t) {
    // ---- stage x_t (f32 -> f16) into xh[:, 0:128] (overlaps the spin)
    if (t < TT) {
#pragma unroll
      for (int ii = 0; ii < 8; ++ii) {
        const int i = ii * 256 + tid;
        const int n = i >> 7, k = i & 127;
        const int row = t * BB + b0 + n;
        float v = (k < 127) ? input[(size_t)row * 127 + k] : dtp[row];
        xh[n][k] = (f16)v;
      }
    }
    // ---- wait for all 16 blocks of the group: ballot-poll 16 flag lines
    if (t > 0 && w == 0) {
      const uint32_t* fp = flg + (size_t)(g * 16 + (lane & 15)) * 16;
      for (;;) {
        uint32_t v = __hip_atomic_load(fp, __ATOMIC_RELAXED,
                                       __HIP_MEMORY_SCOPE_AGENT);
        if (__ballot((lane < 16) ? (v >= (uint32_t)t) : 1) == ~0ull) break;
        __builtin_amdgcn_s_sleep(1);
      }
      // one inv per block per step: drop stale L1/L2 copies of h_buf lines
      __builtin_amdgcn_fence(__ATOMIC_ACQUIRE, "agent");
    }
    __syncthreads();

    // ---- stage h_{t-1} into xh[:, 128:640]: plain cached 16B loads
    // (fresh after the acquire fence; 64B line fills from MALL)
    {
      const f16* hb = h_buf + (size_t)((((t + 1) & 1) * 16) + g) * (16 * HH);
#pragma unroll
      for (int ci = 0; ci < 4; ++ci) {
        const int c = ci * 256 + tid;      // [0, 1024) 16B-chunks
        const int n = c >> 6, q = c & 63;  // 64 chunks per 1024B row
        uint4 v = *(const uint4*)(hb + n * HH + q * 8);
        *(uint4*)(&xh[n][128 + q * 8]) = v;
      }
    }
    __syncthreads();

    if (t < TT) {
      // ---- gates(128x16) = W @ [x_t; h_{t-1}], K = 640
      f32x4 acc0 = {0.f, 0.f, 0.f, 0.f}, acc1 = {0.f, 0.f, 0.f, 0.f};
#pragma unroll
      for (int it = 0; it < 20; ++it) {
        f16x8 b = *(const f16x8*)(&xh[l][it * 32 + quad * 8]);
        acc0 = __builtin_amdgcn_mfma_f32_16x16x32_f16(afrag[0][it], b, acc0, 0, 0, 0);
        acc1 = __builtin_amdgcn_mfma_f32_16x16x32_f16(afrag[1][it], b, acc1, 0, 0, 0);
      }
      // D layout: col = l (n), row = quad*4 + reg (within the 16-row tile)
#pragma unroll
      for (int r = 0; r < 4; ++r) {
        gates_s[w * 32 + quad * 4 + r][l] = acc0[r];
        gates_s[w * 32 + 16 + quad * 4 + r][l] = acc1[r];
      }
      __syncthreads();

      // ---- cell update: thread handles (hl, n) and (hl+16, n)
      {
        const int j = tid >> 4, n = tid & 15;
        float vi = gates_s[j][n] + bias_s[j];
        float vf = gates_s[32 + j][n] + bias_s[32 + j];
        float vg = gates_s[64 + j][n] + bias_s[64 + j];
        float vo = gates_s[96 + j][n] + bias_s[96 + j];
        float iv = sigmoidf_(vi), fv = sigmoidf_(vf);
        float gv = tanhf_(vg), ov = sigmoidf_(vo);
        c0 = fv * c0 + iv * gv;
        h_tile[n][j] = (f16)(ov * tanhf_(c0));

        const int j1 = j + 16;
        float vi1 = gates_s[j1][n] + bias_s[j1];
        float vf1 = gates_s[32 + j1][n] + bias_s[32 + j1];
        float vg1 = gates_s[64 + j1][n] + bias_s[64 + j1];
        float vo1 = gates_s[96 + j1][n] + bias_s[96 + j1];
        float iv1 = sigmoidf_(vi1), fv1 = sigmoidf_(vf1);
        float gv1 = tanhf_(vg1), ov1 = sigmoidf_(vo1);
        c1 = fv1 * c1 + iv1 * gv1;
        h_tile[n][j1] = (f16)(ov1 * tanhf_(c1));
      }
      __syncthreads();

      // ---- publish h slice: 128 threads x one 8B agent atomic store
      // h_buf[t&1][g][n][s*32 + jc..jc+3]
      f16* hw = h_buf + (size_t)(((t & 1) * 16) + g) * (16 * HH) + s * 32;
      if (tid < 128) {
        const int n = tid >> 3, jc = (tid & 7) * 4;
        union {
          f16 h4[4];
          ull u;
        } pk;
        pk.h4[0] = h_tile[n][jc];
        pk.h4[1] = h_tile[n][jc + 1];
        pk.h4[2] = h_tile[n][jc + 2];
        pk.h4[3] = h_tile[n][jc + 3];
        __hip_atomic_store((ull*)(hw + n * HH + jc), pk.u, __ATOMIC_RELAXED,
                           __HIP_MEMORY_SCOPE_AGENT);
      }
      // __syncthreads() drains each wave's vmcnt(0) before s_barrier ->
      // all publishes are at the coherence point before the flag store.
      __syncthreads();
      if (tid == 0)
        __hip_atomic_store(flg + (size_t)(g * 16 + s) * 16, (uint32_t)(t + 1),
                           __ATOMIC_RELAXED, __HIP_MEMORY_SCOPE_AGENT);
    }

    // ---- classifier (off critical path): out[t-1] = W_cls @ h_{t-1} + b_cls
    if (t > 0 && cls_block) {
      f32x4 oacc = {0.f, 0.f, 0.f, 0.f};
#pragma unroll
      for (int it = 0; it < 4; ++it) {
        const int kc = 128 + w * 128 + it * 32 + quad * 8;
        f16x8 b = *(const f16x8*)(&xh[l][kc]);
        oacc = __builtin_amdgcn_mfma_f32_16x16x32_f16(wfrag[it], b, oacc, 0, 0, 0);
      }
#pragma unroll
      for (int r = 0; r < 4; ++r) red[w][quad * 4 + r][l] = oacc[r];
      __syncthreads();
      if (tid < 64) {
        const int n = tid >> 2, m4 = (tid & 3) * 4;
        float4 o;
        float* op = (float*)&o;
#pragma unroll
        for (int r = 0; r < 4; ++r)
          op[r] = red[0][m4 + r][n] + red[1][m4 + r][n] + red[2][m4 + r][n] +
                  red[3][m4 + r][n] + bcls4[r];
        float* obase =
            out + ((size_t)(t - 1) * BB + b0 + n) * NOUTC + mt_o * 16 + m4;
        *(float4*)obase = o;
      }
    }
  }
}

extern "C" void kernel_launch(void* const* d_in, const int* in_sizes, int n_in,
                              void* d_out, int out_size, void* d_ws,
                              size_t ws_size, hipStream_t stream) {
  const float* input = (const float*)d_in[0];
  const float* dtp = (const float*)d_in[1];
  const float* W_ih = (const float*)d_in[2];
  const float* W_hh = (const float*)d_in[3];
  const float* b_ih = (const float*)d_in[4];
  const float* b_hh = (const float*)d_in[5];
  const float* W_cls = (const float*)d_in[6];
  const float* b_cls = (const float*)d_in[7];
  float* out = (float*)d_out;

  // ws layout: [0, 16K): 256 flags, one per 64B line;
  //            [16K, 16K+512K): h double-buffer [2][16][16][512] f16
  uint32_t* flg = (uint32_t*)d_ws;
  f16* h_buf = (f16*)((char*)d_ws + 16384);
  const int nws_words = (16384 + 2 * 16 * 16 * HH * 2) / 4;  // 135168

  zero_ws<<<256, 256, 0, stream>>>(flg, nws_words);
  lstm_kernel<<<256, 256, 0, stream>>>(input, dtp, W_ih, W_hh, b_ih, b_hh,
                                       W_cls, b_cls, out, flg, h_buf);
}